// Round 1
// baseline (159.524 us; speedup 1.0000x reference)
//
#include <hip/hip_runtime.h>

#define NPIX (128 * 128)   // 16384 pixels per channel plane
#define CH 64
#define RMID 16            // CHANNELS / RED
#define GROUPS 32
#define KK 9

// One thread per output pixel (b,h,w); computes all 64 output channels.
// Step 1: t[16] = PReLU(w1 @ x_center + b1)         (1024 FMA)
// Step 2: per group g: 9 weights = w2[g] @ t + b2    (144 FMA)
//         out[2g],out[2g+1] = sum_k wgt[k]*patch     (18 loads + 18 FMA)
__global__ __launch_bounds__(256) void involution_fused(
    const float* __restrict__ x,
    const float* __restrict__ w1,
    const float* __restrict__ b1,
    const float* __restrict__ prelu_a,
    const float* __restrict__ w2,
    const float* __restrict__ b2,
    float* __restrict__ out)
{
    const int tid = blockIdx.x * 256 + threadIdx.x;   // 0 .. 131071
    const int wq  = tid & 127;
    const int hq  = (tid >> 7) & 127;
    const int bq  = tid >> 14;

    const float* xb = x   + (size_t)bq * CH * NPIX;
    float*       ob = out + (size_t)bq * CH * NPIX;
    const int p = hq * 128 + wq;

    // ---- Step 1: t = PReLU(w1 @ x + b1) ----
    float t[RMID];
#pragma unroll
    for (int r = 0; r < RMID; ++r) t[r] = b1[r];

#pragma unroll 4
    for (int c = 0; c < CH; ++c) {
        const float xv = xb[(size_t)c * NPIX + p];
#pragma unroll
        for (int r = 0; r < RMID; ++r)
            t[r] = fmaf(w1[r * CH + c], xv, t[r]);   // w1 read is wave-uniform -> s_load
    }
    const float a = prelu_a[0];
#pragma unroll
    for (int r = 0; r < RMID; ++r)
        t[r] = (t[r] >= 0.f) ? t[r] : a * t[r];

    // ---- neighbor offsets + validity (zero padding) ----
    int  off[KK];
    bool ok[KK];
#pragma unroll
    for (int i = 0; i < 3; ++i) {
#pragma unroll
        for (int j = 0; j < 3; ++j) {
            const int dh = i - 1, dw = j - 1;
            ok[i * 3 + j]  = ((unsigned)(hq + dh) < 128u) && ((unsigned)(wq + dw) < 128u);
            off[i * 3 + j] = dh * 128 + dw;
        }
    }

    // ---- Step 2: per-group weight generation + involution ----
    for (int g = 0; g < GROUPS; ++g) {
        float wg[KK];
#pragma unroll
        for (int k = 0; k < KK; ++k) {
            float acc = b2[g * KK + k];
            const float* w2r = w2 + (g * KK + k) * RMID;  // uniform -> s_load_dwordx16
#pragma unroll
            for (int r = 0; r < RMID; ++r)
                acc = fmaf(w2r[r], t[r], acc);
            wg[k] = acc;
        }

        const float* x0 = xb + (size_t)(2 * g) * NPIX + p;
        const float* x1 = x0 + NPIX;
        float o0 = 0.f, o1 = 0.f;
#pragma unroll
        for (int k = 0; k < KK; ++k) {
            const float p0 = ok[k] ? x0[off[k]] : 0.f;
            const float p1 = ok[k] ? x1[off[k]] : 0.f;
            o0 = fmaf(wg[k], p0, o0);
            o1 = fmaf(wg[k], p1, o1);
        }
        ob[(size_t)(2 * g)     * NPIX + p] = o0;
        ob[(size_t)(2 * g + 1) * NPIX + p] = o1;
    }
}

extern "C" void kernel_launch(void* const* d_in, const int* in_sizes, int n_in,
                              void* d_out, int out_size, void* d_ws, size_t ws_size,
                              hipStream_t stream)
{
    const float* x  = (const float*)d_in[0];
    const float* w1 = (const float*)d_in[1];
    const float* b1 = (const float*)d_in[2];
    const float* pa = (const float*)d_in[3];
    const float* w2 = (const float*)d_in[4];
    const float* b2 = (const float*)d_in[5];
    float* out = (float*)d_out;

    const int total = 8 * NPIX;              // 131072 threads, 1 per pixel
    dim3 grid(total / 256), block(256);
    hipLaunchKernelGGL(involution_fused, grid, block, 0, stream,
                       x, w1, b1, pa, w2, b2, out);
}